// Round 7
// baseline (523.510 us; speedup 1.0000x reference)
//
#include <hip/hip_runtime.h>

#define HEADS 6
#define N_TOK 144
#define DIM   192
#define NW    64
#define NB    15
#define NBW   (NB * NW)          // 960

typedef __attribute__((ext_vector_type(8))) short bf16x8;
typedef __attribute__((ext_vector_type(4))) float f32x4;

#define MFMA(a, b, c) __builtin_amdgcn_mfma_f32_16x16x32_bf16(a, b, c, 0, 0, 0)

static __device__ __forceinline__ short f2bf(float f) {
    union { float f; unsigned u; } v; v.f = f;
    unsigned r = v.u + 0x7FFFu + ((v.u >> 16) & 1u);   // RNE
    return (short)(r >> 16);
}
static __device__ __forceinline__ float bf2f(short s) {
    union { unsigned u; float f; } v;
    v.u = ((unsigned)(unsigned short)s) << 16;
    return v.f;
}
static __device__ __forceinline__ unsigned pk2(float a, float b) {
    return (unsigned)(unsigned short)f2bf(a) |
           ((unsigned)(unsigned short)f2bf(b) << 16);
}

// ---------------------------------------------------------------------------
// K0a: bias gather -> bf16, layout [(w*6+h)][i*144+j].
// ---------------------------------------------------------------------------
__global__ __launch_bounds__(256)
void bias_k(const float* __restrict__ table, const int* __restrict__ pos_index,
            short* __restrict__ bias_bf) {
    const int t = blockIdx.x;                      // w*6+h, 0..383
    for (int e = threadIdx.x; e < N_TOK * N_TOK; e += 256) {
        int idx = pos_index[e];
        bias_bf[(long)t * (N_TOK * N_TOK) + e] = f2bf(table[(long)idx * 384 + t]);
    }
}

// K0b: f32 -> bf16 copy (weights)
__global__ __launch_bounds__(256)
void cvt_k(const float* __restrict__ w, short* __restrict__ o, int n) {
    int i = blockIdx.x * 256 + threadIdx.x;
    if (i < n) o[i] = f2bf(w[i]);
}

// ---------------------------------------------------------------------------
// K1: fused QKV + attention. Block = bw (960), 9 waves, wave = 16 q-rows.
// Wave's 16 x-rows held in regs as 6 bf16x8 A-frags (loaded once).
// Per head h:
//   GEMM: acc[sel][nt] += MFMA(af[ks], W-frag from L2 bf16 qkv_w)  (36 MFMA)
//   q -> per-wave pws [16][40] (private, no barrier);
//   barrier; k -> klds[144][40], v -> vlds[32][152] (transposed); barrier;
//   swapped QK^T: lgt = MFMA(K-tile, Q-tile) -> lane holds S[k 4-consec][q];
//   bias short4 + mask float4 loads (L2 after h=0); softmax (2 shuffles);
//   P packed -> pws streaming; PV = MFMA(V^T, P); coalesced short4 tmp write.
// ---------------------------------------------------------------------------
__global__ __launch_bounds__(576, 4)
void fused_k(const float* __restrict__ x, const short* __restrict__ qkvw_bf,
             const float* __restrict__ qkv_b, const short* __restrict__ bias_bf,
             const float* __restrict__ mask, short* __restrict__ tmp) {
    __shared__ short klds[N_TOK * 40];     // 11,520 B
    __shared__ short vlds[32 * 152];       //  9,728 B
    __shared__ short pws[9 * 16 * 40];     // 11,520 B

    const int bw  = blockIdx.x;
    const int tid = threadIdx.x;
    const int lane = tid & 63, lq = lane & 15, lg = lane >> 4;
    const int wid = tid >> 6;
    const int m0 = wid * 16;
    const int q  = m0 + lq;                // this lane's query/x row
    const int w  = bw & 63;
    const float scale = 0.17677669529663687f;   // 32^-0.5

    // ---- x A-frags (row q, all 192 k) in registers ----
    bf16x8 af[6];
    {
        const float* xg = x + ((long)bw * N_TOK + q) * DIM;
        #pragma unroll
        for (int ks = 0; ks < 6; ++ks) {
            const float4* p = (const float4*)&xg[ks * 32 + 8 * lg];
            float4 f0 = p[0], f1 = p[1];
            bf16x8 a;
            a[0]=f2bf(f0.x); a[1]=f2bf(f0.y); a[2]=f2bf(f0.z); a[3]=f2bf(f0.w);
            a[4]=f2bf(f1.x); a[5]=f2bf(f1.y); a[6]=f2bf(f1.z); a[7]=f2bf(f1.w);
            af[ks] = a;
        }
    }

    short* pw = pws + wid * 16 * 40;
    short* tb = tmp + ((long)bw * N_TOK + q) * DIM;
    const float* mp = mask + (long)bw * (N_TOK * N_TOK) + q * N_TOK + 4 * lg;
    const f32x4 zf = {};
    const bf16x8 zb = {};

    #pragma unroll 1
    for (int h = 0; h < HEADS; ++h) {
        // ---- qkv GEMM for head h ----
        f32x4 acc[3][2] = {};
        #pragma unroll
        for (int sel = 0; sel < 3; ++sel) {
            const short* wb = qkvw_bf + ((long)sel * 192 + h * 32) * 192;
            #pragma unroll
            for (int ks = 0; ks < 6; ++ks) {
                #pragma unroll
                for (int nt = 0; nt < 2; ++nt) {
                    bf16x8 b = *(const bf16x8*)&wb[(nt * 16 + lq) * 192 + ks * 32 + 8 * lg];
                    acc[sel][nt] = MFMA(af[ks], b, acc[sel][nt]);
                }
            }
        }

        // q -> per-wave pw (private region: same wave finished reading it)
        #pragma unroll
        for (int nt = 0; nt < 2; ++nt) {
            float bb = qkv_b[h * 32 + nt * 16 + lq];
            #pragma unroll
            for (int i = 0; i < 4; ++i)
                pw[(4 * lg + i) * 40 + nt * 16 + lq] =
                    f2bf((acc[0][nt][i] + bb) * scale);
        }

        __syncthreads();   // all waves done reading prev head's klds/vlds

        #pragma unroll
        for (int nt = 0; nt < 2; ++nt) {
            float bk = qkv_b[192 + h * 32 + nt * 16 + lq];
            float bv = qkv_b[384 + h * 32 + nt * 16 + lq];
            #pragma unroll
            for (int i = 0; i < 4; ++i) {
                klds[(m0 + 4 * lg + i) * 40 + nt * 16 + lq] = f2bf(acc[1][nt][i] + bk);
                vlds[(nt * 16 + lq) * 152 + m0 + 4 * lg + i] = f2bf(acc[2][nt][i] + bv);
            }
        }
        __syncthreads();   // k, v visible

        // ---- QK^T (swapped: A=K tile, B=Q tile) ----
        bf16x8 bq = *(const bf16x8*)&pw[lq * 40 + 8 * lg];
        f32x4 lgt[9];
        #pragma unroll
        for (int nt = 0; nt < 9; ++nt) {
            bf16x8 ak = *(const bf16x8*)&klds[(nt * 16 + lq) * 40 + 8 * lg];
            lgt[nt] = MFMA(ak, bq, zf);
        }

        // ---- + bias (short4) + mask (float4) ----
        const short* bp = bias_bf + (long)(w * 6 + h) * (N_TOK * N_TOK)
                        + q * N_TOK + 4 * lg;
        #pragma unroll
        for (int nt = 0; nt < 9; ++nt) {
            short4 bs = *(const short4*)&bp[nt * 16];
            float4 mf = *(const float4*)&mp[nt * 16];
            lgt[nt][0] += bf2f(bs.x) + mf.x;
            lgt[nt][1] += bf2f(bs.y) + mf.y;
            lgt[nt][2] += bf2f(bs.z) + mf.z;
            lgt[nt][3] += bf2f(bs.w) + mf.w;
        }

        // ---- softmax over k (36 in-lane + xor16/xor32) ----
        float m = lgt[0][0];
        #pragma unroll
        for (int nt = 0; nt < 9; ++nt)
            #pragma unroll
            for (int i = 0; i < 4; ++i) m = fmaxf(m, lgt[nt][i]);
        m = fmaxf(m, __shfl_xor(m, 16));
        m = fmaxf(m, __shfl_xor(m, 32));
        float s = 0.f;
        #pragma unroll
        for (int nt = 0; nt < 9; ++nt)
            #pragma unroll
            for (int i = 0; i < 4; ++i) {
                float p = __expf(lgt[nt][i] - m);
                lgt[nt][i] = p;
                s += p;
            }
        s += __shfl_xor(s, 16);
        s += __shfl_xor(s, 32);
        const float inv = 1.f / s;

        // ---- PV: stream packed P through pw; o = MFMA(V^T, P) ----
        f32x4 o[2] = {};
        #pragma unroll
        for (int kt = 0; kt < 5; ++kt) {
            const int nt0 = 2 * kt;
            *(unsigned*)&pw[lq * 40 + 4 * lg]     = pk2(lgt[nt0][0], lgt[nt0][1]);
            *(unsigned*)&pw[lq * 40 + 4 * lg + 2] = pk2(lgt[nt0][2], lgt[nt0][3]);
            if (kt < 4) {
                const int nt1 = nt0 + 1;
                *(unsigned*)&pw[lq * 40 + 16 + 4 * lg]     = pk2(lgt[nt1][0], lgt[nt1][1]);
                *(unsigned*)&pw[lq * 40 + 16 + 4 * lg + 2] = pk2(lgt[nt1][2], lgt[nt1][3]);
            }
            bf16x8 bpf = *(const bf16x8*)&pw[lq * 40 + 8 * lg];
            #pragma unroll
            for (int et = 0; et < 2; ++et) {
                bf16x8 av = *(const bf16x8*)&vlds[(et * 16 + lq) * 152 + kt * 32 + 8 * lg];
                bf16x8 aa = av, bb = bpf;
                if (kt == 4 && lg >= 2) { aa = zb; bb = zb; }   // keys 144..159
                o[et] = MFMA(aa, bb, o[et]);
            }
        }

        // ---- write tmp[bw][q][h*32 + e] (short4) ----
        #pragma unroll
        for (int et = 0; et < 2; ++et) {
            short4 sx = { f2bf(o[et][0] * inv), f2bf(o[et][1] * inv),
                          f2bf(o[et][2] * inv), f2bf(o[et][3] * inv) };
            *(short4*)&tb[h * 32 + et * 16 + 4 * lg] = sx;
        }
    }
}

// ---------------------------------------------------------------------------
// K2: output projection. Block = (bw, m-third), 3 waves, wave = 16 rows.
// A from tmp bf16 (16B loads), B from L2-resident bf16 proj_w. No LDS.
// ---------------------------------------------------------------------------
__global__ __launch_bounds__(192)
void proj_k(const short* __restrict__ tmp, const short* __restrict__ pwt,
            const float* __restrict__ proj_b, float* __restrict__ out) {
    const int bid = blockIdx.x;
    const int mthird = bid % 3;
    const int bw = bid / 3;
    const int tid = threadIdx.x;
    const int wid = tid >> 6, lane = tid & 63, lq = lane & 15, lg = lane >> 4;
    const int m0 = (mthird * 3 + wid) * 16;
    const short* tb = tmp + (long)bw * N_TOK * DIM;

    f32x4 acc[12] = {};
    for (int ks = 0; ks < 6; ++ks) {
        const int k0 = ks * 32 + 8 * lg;
        bf16x8 a = *(const bf16x8*)&tb[(m0 + lq) * DIM + k0];
        #pragma unroll
        for (int nt = 0; nt < 12; ++nt) {
            bf16x8 b = *(const bf16x8*)&pwt[(nt * 16 + lq) * DIM + k0];
            acc[nt] = MFMA(a, b, acc[nt]);
        }
    }
    float* ob = out + (long)bw * N_TOK * DIM;
    #pragma unroll
    for (int nt = 0; nt < 12; ++nt) {
        float pb = proj_b[nt * 16 + lq];
        #pragma unroll
        for (int i = 0; i < 4; ++i)
            ob[(m0 + 4 * lg + i) * DIM + nt * 16 + lq] = acc[nt][i] + pb;
    }
}

// ---------------------------------------------------------------------------
extern "C" void kernel_launch(void* const* d_in, const int* in_sizes, int n_in,
                              void* d_out, int out_size, void* d_ws, size_t ws_size,
                              hipStream_t stream) {
    const float* x        = (const float*)d_in[0];
    const float* mask     = (const float*)d_in[1];
    const float* qkv_w    = (const float*)d_in[2];
    const float* qkv_b    = (const float*)d_in[3];
    const float* table    = (const float*)d_in[4];
    const float* proj_w   = (const float*)d_in[5];
    const float* proj_b   = (const float*)d_in[6];
    const int*   pos_index= (const int*)d_in[7];
    float* out = (float*)d_out;

    // ws layout (bf16 shorts), total ~69.3 MB:
    //  bias_bf  [384][144*144]        15.93 MB
    //  projw_bf [192*192]              0.07 MB
    //  qkvw_bf  [576*192]              0.22 MB
    //  tmp_ws   [960 x 144 x 192]     53.08 MB
    short* bias_bf  = (short*)d_ws;
    short* projw_bf = bias_bf + (size_t)384 * N_TOK * N_TOK;
    short* qkvw_bf  = projw_bf + 36864;
    short* tmp_ws   = qkvw_bf + 110592;

    bias_k<<<384, 256, 0, stream>>>(table, pos_index, bias_bf);
    cvt_k<<<144, 256, 0, stream>>>(proj_w, projw_bf, DIM * DIM);
    cvt_k<<<432, 256, 0, stream>>>(qkv_w, qkvw_bf, 3 * DIM * DIM);

    fused_k<<<NBW, 576, 0, stream>>>(x, qkvw_bf, qkv_b, bias_bf, mask, tmp_ws);
    proj_k<<<NBW * 3, 192, 0, stream>>>(tmp_ws, projw_bf, proj_b, out);
}

// Round 8
// 445.148 us; speedup vs baseline: 1.1760x; 1.1760x over previous
//
#include <hip/hip_runtime.h>

#define HEADS 6
#define N_TOK 144
#define DIM   192
#define NW    64
#define NB    15
#define NBW   (NB * NW)          // 960
#define CHUNK 480                // bw per chunk (2 chunks)

typedef __attribute__((ext_vector_type(8))) short bf16x8;
typedef __attribute__((ext_vector_type(4))) float f32x4;

#define MFMA(a, b, c) __builtin_amdgcn_mfma_f32_16x16x32_bf16(a, b, c, 0, 0, 0)

static __device__ __forceinline__ short f2bf(float f) {
    union { float f; unsigned u; } v; v.f = f;
    unsigned r = v.u + 0x7FFFu + ((v.u >> 16) & 1u);   // RNE
    return (short)(r >> 16);
}
static __device__ __forceinline__ float bf2f(short s) {
    union { unsigned u; float f; } v;
    v.u = ((unsigned)(unsigned short)s) << 16;
    return v.f;
}
static __device__ __forceinline__ unsigned pk2(float a, float b) {
    return (unsigned)(unsigned short)f2bf(a) |
           ((unsigned)(unsigned short)f2bf(b) << 16);
}

// ---------------------------------------------------------------------------
// K0a: bias gather -> bf16, layout [(w*6+h)][i*144+j].
// ---------------------------------------------------------------------------
__global__ __launch_bounds__(256)
void bias_k(const float* __restrict__ table, const int* __restrict__ pos_index,
            short* __restrict__ bias_bf) {
    const int t = blockIdx.x;                      // w*6+h, 0..383
    for (int e = threadIdx.x; e < N_TOK * N_TOK; e += 256) {
        int idx = pos_index[e];
        bias_bf[(long)t * (N_TOK * N_TOK) + e] = f2bf(table[(long)idx * 384 + t]);
    }
}

// K0b: f32 -> bf16 scalar copy (weights)
__global__ __launch_bounds__(256)
void cvt_k(const float* __restrict__ w, short* __restrict__ o, int n) {
    int i = blockIdx.x * 256 + threadIdx.x;
    if (i < n) o[i] = f2bf(w[i]);
}

// K0c: f32 -> bf16 vectorized (x, per chunk)
__global__ __launch_bounds__(256)
void cvtx_k(const float* __restrict__ x, short* __restrict__ xb, int n4) {
    int i = blockIdx.x * 256 + threadIdx.x;
    if (i < n4) {
        float4 f = ((const float4*)x)[i];
        short4 s = { f2bf(f.x), f2bf(f.y), f2bf(f.z), f2bf(f.w) };
        ((short4*)xb)[i] = s;
    }
}

// ---------------------------------------------------------------------------
// K1: QKV GEMM (R4/R6-proven core). Block = (bwL, sel). W_sel in LDS
// (stride 200). 9 waves = 3mg x 3ng, wave tile 48x64, K = 6x32.
// Epilogues (all coalesced bf16x8 global stores via LDS restage):
//   sel 0/1 (q,k): row-major restage [144][200] -> qk_ws[bwL][h][sel][row][e]
//   sel 2   (v)  : col-major restage [192][152] -> vT_ws[bwL][h][e][row]
// q pre-scaled by 32^-0.5.
// ---------------------------------------------------------------------------
__global__ __launch_bounds__(576)
void qkvs_k(const short* __restrict__ xb, const short* __restrict__ qkvw_bf,
            const float* __restrict__ qkv_b, short* __restrict__ qk_ws,
            short* __restrict__ vT_ws) {
    __shared__ short wlds[192 * 200];   // W_sel [oc][k]; reused for out staging

    const int sel = blockIdx.x % 3;
    const int bwL = blockIdx.x / 3;
    const int tid = threadIdx.x;

    for (int u = tid * 8; u < 192 * 192; u += 576 * 8) {
        int r = u / 192, c = u - r * 192;
        *(bf16x8*)&wlds[r * 200 + c] = *(const bf16x8*)&qkvw_bf[sel * 36864 + u];
    }
    __syncthreads();

    const int wid = tid >> 6, lane = tid & 63, lq = lane & 15, lg = lane >> 4;
    const int mg = wid / 3, ng = wid % 3;
    const short* xrow = xb + (long)bwL * N_TOK * DIM;

    f32x4 acc[3][4] = {};
    for (int ks = 0; ks < 6; ++ks) {
        const int k0 = ks * 32 + 8 * lg;
        bf16x8 av[3], bv[4];
        #pragma unroll
        for (int mt = 0; mt < 3; ++mt)
            av[mt] = *(const bf16x8*)&xrow[(mg * 48 + mt * 16 + lq) * DIM + k0];
        #pragma unroll
        for (int nt = 0; nt < 4; ++nt)
            bv[nt] = *(const bf16x8*)&wlds[(ng * 64 + nt * 16 + lq) * 200 + k0];
        #pragma unroll
        for (int mt = 0; mt < 3; ++mt)
            #pragma unroll
            for (int nt = 0; nt < 4; ++nt)
                acc[mt][nt] = MFMA(av[mt], bv[nt], acc[mt][nt]);
    }
    __syncthreads();   // done reading W -> reuse wlds

    const float scale = 0.17677669529663687f;   // 32^-0.5

    if (sel < 2) {
        // ---- row-major restage [144][200] ----
        #pragma unroll
        for (int nt = 0; nt < 4; ++nt) {
            const int cd = ng * 64 + nt * 16 + lq;          // 0..191
            const float bb = qkv_b[sel * 192 + cd];
            #pragma unroll
            for (int mt = 0; mt < 3; ++mt)
                #pragma unroll
                for (int i = 0; i < 4; ++i) {
                    int row = mg * 48 + mt * 16 + 4 * lg + i;
                    float v = acc[mt][nt][i] + bb;
                    if (sel == 0) v *= scale;
                    wlds[row * 200 + cd] = f2bf(v);
                }
        }
        __syncthreads();
        short* ob = qk_ws + (long)bwL * 6 * 2 * 4608 + (long)sel * 4608;
        #pragma unroll
        for (int j = 0; j < 6; ++j) {
            int u = (j * 576 + tid) * 8;        // 0..27647
            int h = u / 4608, rem = u - h * 4608;
            int row = rem >> 5, e = rem & 31;
            *(bf16x8*)&ob[(long)h * 2 * 4608 + rem] =
                *(const bf16x8*)&wlds[row * 200 + h * 32 + e];
        }
    } else {
        // ---- col-major restage [192][152] (2-way-free scalar writes) ----
        #pragma unroll
        for (int nt = 0; nt < 4; ++nt) {
            const int cd = ng * 64 + nt * 16 + lq;          // 0..191
            const float bb = qkv_b[2 * 192 + cd];
            #pragma unroll
            for (int mt = 0; mt < 3; ++mt)
                #pragma unroll
                for (int i = 0; i < 4; ++i) {
                    int row = mg * 48 + mt * 16 + 4 * lg + i;
                    wlds[cd * 152 + row] = f2bf(acc[mt][nt][i] + bb);
                }
        }
        __syncthreads();
        short* ob = vT_ws + (long)bwL * 6 * 4608;
        #pragma unroll
        for (int j = 0; j < 6; ++j) {
            int u = (j * 576 + tid) * 8;        // 0..27647
            int h = u / 4608, rem = u - h * 4608;
            int e = rem / 144, row0 = rem - e * 144;   // row0 multiple of 8
            *(bf16x8*)&ob[(long)h * 4608 + e * 144 + row0] =
                *(const bf16x8*)&wlds[(h * 32 + e) * 152 + row0];
        }
    }
}

// ---------------------------------------------------------------------------
// K2: attention. Block = (bwL, head) via XCD-chunked swizzle (all 6 heads of
// a bw land on the same XCD -> mask L2-reuse). 9 waves x 16 q-rows.
// Swapped QK^T: lane holds S[k 4-consec][q]; bias short4 + mask float4;
// softmax 2 shuffles; P packed -> per-wave LDS; PV = MFMA(V^T, P).
// ---------------------------------------------------------------------------
__global__ __launch_bounds__(576)
void attn2v_k(const short* __restrict__ qk_ws, const short* __restrict__ vT_ws,
              const short* __restrict__ bias_bf, const float* __restrict__ mask,
              short* __restrict__ tmp, int bw0) {
    __shared__ short vlds[32 * 152];      //  9,728 B
    __shared__ short pws[9 * 16 * 40];    // 11,520 B

    // bijective XCD-chunk swizzle: grid = 2880 = 8 * 360
    const int p = blockIdx.x;
    const int l = (p & 7) * 360 + (p >> 3);
    const int h   = l % HEADS;
    const int bwL = l / HEADS;
    const int bwG = bw0 + bwL;
    const int tid = threadIdx.x;
    const int lane = tid & 63, lq = lane & 15, lg = lane >> 4;
    const int wid = tid >> 6;
    const int m0 = wid * 16;
    const int q  = m0 + lq;
    const int w  = bwG & 63;

    // stage V^T -> vlds [32][152]: one 16B load + one 16B LDS write per thread
    {
        const short* vsrc = vT_ws + (long)(bwL * 6 + h) * 4608;
        int e = tid / 18, k0 = (tid % 18) * 8;
        bf16x8 v = *(const bf16x8*)&vsrc[e * N_TOK + k0];
        *(bf16x8*)&vlds[e * 152 + k0] = v;
    }
    __syncthreads();

    const short* qb = qk_ws + (long)(bwL * 6 + h) * 2 * 4608;
    const short* kb = qb + 4608;

    // ---- QK^T (swapped: A=K tile, B=Q tile) ----
    const f32x4 zf = {};
    bf16x8 bq = *(const bf16x8*)&qb[q * 32 + 8 * lg];
    f32x4 lgt[9];
    #pragma unroll
    for (int nt = 0; nt < 9; ++nt) {
        bf16x8 ak = *(const bf16x8*)&kb[(nt * 16 + lq) * 32 + 8 * lg];
        lgt[nt] = MFMA(ak, bq, zf);
    }

    // ---- + bias (short4) + mask (float4) ----
    const short* bp = bias_bf + (long)(w * 6 + h) * (N_TOK * N_TOK)
                    + q * N_TOK + 4 * lg;
    const float* mp = mask + (long)bwG * (N_TOK * N_TOK) + q * N_TOK + 4 * lg;
    #pragma unroll
    for (int nt = 0; nt < 9; ++nt) {
        short4 bs = *(const short4*)&bp[nt * 16];
        float4 mf = *(const float4*)&mp[nt * 16];
        lgt[nt][0] += bf2f(bs.x) + mf.x;
        lgt[nt][1] += bf2f(bs.y) + mf.y;
        lgt[nt][2] += bf2f(bs.z) + mf.z;
        lgt[nt][3] += bf2f(bs.w) + mf.w;
    }

    // ---- softmax over k (36 in-lane + xor16/xor32) ----
    float m = lgt[0][0];
    #pragma unroll
    for (int nt = 0; nt < 9; ++nt)
        #pragma unroll
        for (int i = 0; i < 4; ++i) m = fmaxf(m, lgt[nt][i]);
    m = fmaxf(m, __shfl_xor(m, 16));
    m = fmaxf(m, __shfl_xor(m, 32));
    float s = 0.f;
    #pragma unroll
    for (int nt = 0; nt < 9; ++nt)
        #pragma unroll
        for (int i = 0; i < 4; ++i) {
            float pe = __expf(lgt[nt][i] - m);
            lgt[nt][i] = pe;
            s += pe;
        }
    s += __shfl_xor(s, 16);
    s += __shfl_xor(s, 32);
    const float inv = 1.f / s;

    // ---- PV: stream packed P through per-wave LDS [16][40] ----
    short* pw = pws + wid * 16 * 40;
    f32x4 o[2] = {};
    const bf16x8 zb = {};
    #pragma unroll
    for (int kt = 0; kt < 5; ++kt) {
        const int nt0 = 2 * kt;
        *(unsigned*)&pw[lq * 40 + 4 * lg]     = pk2(lgt[nt0][0], lgt[nt0][1]);
        *(unsigned*)&pw[lq * 40 + 4 * lg + 2] = pk2(lgt[nt0][2], lgt[nt0][3]);
        if (kt < 4) {
            const int nt1 = nt0 + 1;
            *(unsigned*)&pw[lq * 40 + 16 + 4 * lg]     = pk2(lgt[nt1][0], lgt[nt1][1]);
            *(unsigned*)&pw[lq * 40 + 16 + 4 * lg + 2] = pk2(lgt[nt1][2], lgt[nt1][3]);
        }
        bf16x8 bpf = *(const bf16x8*)&pw[lq * 40 + 8 * lg];
        #pragma unroll
        for (int et = 0; et < 2; ++et) {
            bf16x8 av = *(const bf16x8*)&vlds[(et * 16 + lq) * 152 + kt * 32 + 8 * lg];
            bf16x8 aa = av, bb = bpf;
            if (kt == 4 && lg >= 2) { aa = zb; bb = zb; }   // keys 144..159
            o[et] = MFMA(aa, bb, o[et]);
        }
    }

    // ---- write tmp[bwL][q][h*32 + e] (short4) ----
    short* tb = tmp + ((long)bwL * N_TOK + q) * DIM + h * 32;
    #pragma unroll
    for (int et = 0; et < 2; ++et) {
        short4 sx = { f2bf(o[et][0] * inv), f2bf(o[et][1] * inv),
                      f2bf(o[et][2] * inv), f2bf(o[et][3] * inv) };
        *(short4*)&tb[et * 16 + 4 * lg] = sx;
    }
}

// ---------------------------------------------------------------------------
// K3: output projection. Block = (bwL, m-third), 3 waves, wave = 16 rows.
// ---------------------------------------------------------------------------
__global__ __launch_bounds__(192)
void proj_k(const short* __restrict__ tmp, const short* __restrict__ pwt,
            const float* __restrict__ proj_b, float* __restrict__ out, int bw0) {
    const int bid = blockIdx.x;
    const int mthird = bid % 3;
    const int bwL = bid / 3;
    const int bwG = bw0 + bwL;
    const int tid = threadIdx.x;
    const int wid = tid >> 6, lane = tid & 63, lq = lane & 15, lg = lane >> 4;
    const int m0 = (mthird * 3 + wid) * 16;
    const short* tb = tmp + (long)bwL * N_TOK * DIM;

    f32x4 acc[12] = {};
    for (int ks = 0; ks < 6; ++ks) {
        const int k0 = ks * 32 + 8 * lg;
        bf16x8 a = *(const bf16x8*)&tb[(m0 + lq) * DIM + k0];
        #pragma unroll
        for (int nt = 0; nt < 12; ++nt) {
            bf16x8 b = *(const bf16x8*)&pwt[(nt * 16 + lq) * DIM + k0];
            acc[nt] = MFMA(a, b, acc[nt]);
        }
    }
    float* ob = out + (long)bwG * N_TOK * DIM;
    #pragma unroll
    for (int nt = 0; nt < 12; ++nt) {
        float pb = proj_b[nt * 16 + lq];
        #pragma unroll
        for (int i = 0; i < 4; ++i)
            ob[(m0 + 4 * lg + i) * DIM + nt * 16 + lq] = acc[nt][i] + pb;
    }
}

// ---------------------------------------------------------------------------
extern "C" void kernel_launch(void* const* d_in, const int* in_sizes, int n_in,
                              void* d_out, int out_size, void* d_ws, size_t ws_size,
                              hipStream_t stream) {
    const float* x        = (const float*)d_in[0];
    const float* mask     = (const float*)d_in[1];
    const float* qkv_w    = (const float*)d_in[2];
    const float* qkv_b    = (const float*)d_in[3];
    const float* table    = (const float*)d_in[4];
    const float* proj_w   = (const float*)d_in[5];
    const float* proj_b   = (const float*)d_in[6];
    const int*   pos_index= (const int*)d_in[7];
    float* out = (float*)d_out;

    // ws layout (bf16 shorts), total 122.4 MB (== proven footprint):
    //  bias_bf  [384][144*144]            15.93 MB
    //  projw_bf [192*192]                  0.07 MB
    //  qkvw_bf  [576*192]                  0.22 MB
    //  xbf/tmp  [CHUNK x 144 x 192]       26.54 MB (xbf dead after qkvs ->
    //                                               tmp aliases it)
    //  qk_ws    [CHUNK*6][2][144][32]     53.08 MB (per chunk)
    //  vT_ws    [CHUNK*6][32][144]        26.54 MB (per chunk)
    short* bias_bf  = (short*)d_ws;
    short* projw_bf = bias_bf + (size_t)384 * N_TOK * N_TOK;
    short* qkvw_bf  = projw_bf + 36864;
    short* xbf_ws   = qkvw_bf + 110592;
    short* tmp_ws   = xbf_ws;                       // alias (see above)
    short* qk_ws    = xbf_ws + (size_t)CHUNK * N_TOK * DIM;
    short* vT_ws    = qk_ws + (size_t)CHUNK * 6 * 2 * 4608;

    bias_k<<<384, 256, 0, stream>>>(table, pos_index, bias_bf);
    cvt_k<<<144, 256, 0, stream>>>(proj_w, projw_bf, DIM * DIM);
    cvt_k<<<432, 256, 0, stream>>>(qkv_w, qkvw_bf, 3 * DIM * DIM);

    const int n4 = CHUNK * N_TOK * DIM / 4;   // 3,317,760
    for (int c = 0; c < 2; ++c) {
        const int bw0 = c * CHUNK;
        cvtx_k<<<(n4 + 255) / 256, 256, 0, stream>>>(
            x + (long)bw0 * N_TOK * DIM, xbf_ws, n4);
        qkvs_k<<<CHUNK * 3, 576, 0, stream>>>(xbf_ws, qkvw_bf, qkv_b,
                                              qk_ws, vT_ws);
        attn2v_k<<<CHUNK * 6, 576, 0, stream>>>(qk_ws, vT_ws, bias_bf, mask,
                                                tmp_ws, bw0);
        proj_k<<<CHUNK * 3, 192, 0, stream>>>(tmp_ws, projw_bf, proj_b, out, bw0);
    }
}